// Round 6
// baseline (381.547 us; speedup 1.0000x reference)
//
#include <hip/hip_runtime.h>
#include <hip/hip_bf16.h>
#include <stdint.h>

#define B_ 2
#define T_ 2048
#define HID_ 2048
#define H_ 16
#define KVH_ 4
#define D_ 128

typedef __attribute__((ext_vector_type(8))) short short8;
typedef __attribute__((ext_vector_type(4))) float f32x4;

__device__ __forceinline__ uint16_t f2bf(float x) {
  union { float f; uint32_t u; } c; c.f = x;
  uint32_t r = c.u + 0x7fffu + ((c.u >> 16) & 1u);
  return (uint16_t)(r >> 16);
}
__device__ __forceinline__ float bf2f(uint16_t b) {
  union { uint32_t u; float f; } c; c.u = ((uint32_t)b) << 16;
  return c.f;
}
__device__ __forceinline__ uint16_t hwbf(float x) {
  __hip_bfloat16 h = __float2bfloat16(x);
  return *reinterpret_cast<uint16_t*>(&h);
}

// ---------------- fp32 -> bf16 convert ----------------
__global__ __launch_bounds__(256) void cvt_f32_bf16(const float* __restrict__ in,
                                                    uint16_t* __restrict__ out, int n) {
  int i = (blockIdx.x * 256 + threadIdx.x) * 4;
  if (i >= n) return;
  const float4 v = *reinterpret_cast<const float4*>(in + i);
  union { uint16_t s[4]; uint2 u; } pk;
  pk.s[0] = f2bf(v.x); pk.s[1] = f2bf(v.y); pk.s[2] = f2bf(v.z); pk.s[3] = f2bf(v.w);
  *reinterpret_cast<uint2*>(out + i) = pk.u;
}

__global__ __launch_bounds__(256) void concat_bias(const float* __restrict__ bq,
                                                   const float* __restrict__ bk,
                                                   const float* __restrict__ bv,
                                                   float* __restrict__ out) {
  int i = blockIdx.x * 256 + threadIdx.x;
  if (i < 2048) out[i] = bq[i];
  else if (i < 2560) out[i] = bk[i - 2048];
  else if (i < 3072) out[i] = bv[i - 2560];
}

// ---------------- bt-GEMM: A[M][K] bf16, Bt[N][K] bf16 -> C[M][N] ----------------
#define BM 128
#define BN 128
#define BK 64

template<bool OUT_F32, bool HAS_BIAS>
__global__ __launch_bounds__(256) void gemm_bt(const uint16_t* __restrict__ A,
                                               const uint16_t* __restrict__ Bt,
                                               void* __restrict__ Cv,
                                               const float* __restrict__ bias,
                                               int M, int N, int K) {
  __shared__ __align__(16) uint16_t Al[BM * BK];
  __shared__ __align__(16) uint16_t Bl[BN * BK];
  const int tid = threadIdx.x;
  const int w = tid >> 6;
  const int lane = tid & 63;
  const int wr = w >> 1, wc = w & 1;
  const int bm = blockIdx.y * BM;
  const int bn = blockIdx.x * BN;
  const int lm = lane & 15, lg = lane >> 4;
  const int srow = lane >> 3, scol = (lane & 7) * 8;

  f32x4 acc[4][4];
  const f32x4 z4 = {0.f, 0.f, 0.f, 0.f};
#pragma unroll
  for (int i = 0; i < 4; ++i)
#pragma unroll
    for (int j = 0; j < 4; ++j) acc[i][j] = z4;

  for (int k0 = 0; k0 < K; k0 += BK) {
#pragma unroll
    for (int i = 0; i < 4; ++i) {
      const int c = i * 4 + w;
      const int row = c * 8 + srow;
      const uint16_t* gA = A + (size_t)(bm + row) * K + k0 + scol;
      const uint16_t* gB = Bt + (size_t)(bn + row) * K + k0 + scol;
      __builtin_amdgcn_global_load_lds((const __attribute__((address_space(1))) unsigned int*)gA,
                                       (__attribute__((address_space(3))) unsigned int*)(Al + c * 512),
                                       16, 0, 0);
      __builtin_amdgcn_global_load_lds((const __attribute__((address_space(1))) unsigned int*)gB,
                                       (__attribute__((address_space(3))) unsigned int*)(Bl + c * 512),
                                       16, 0, 0);
    }
    __syncthreads();
#pragma unroll
    for (int kk = 0; kk < 2; ++kk) {
      const int ko = kk * 32 + lg * 8;
      short8 af[4], bfr[4];
#pragma unroll
      for (int mi = 0; mi < 4; ++mi)
        af[mi] = *reinterpret_cast<const short8*>(Al + (wr * 64 + mi * 16 + lm) * BK + ko);
#pragma unroll
      for (int ni = 0; ni < 4; ++ni)
        bfr[ni] = *reinterpret_cast<const short8*>(Bl + (wc * 64 + ni * 16 + lm) * BK + ko);
#pragma unroll
      for (int mi = 0; mi < 4; ++mi)
#pragma unroll
        for (int ni = 0; ni < 4; ++ni)
          acc[mi][ni] = __builtin_amdgcn_mfma_f32_16x16x32_bf16(af[mi], bfr[ni], acc[mi][ni], 0, 0, 0);
    }
    __syncthreads();
  }

#pragma unroll
  for (int mi = 0; mi < 4; ++mi) {
#pragma unroll
    for (int ni = 0; ni < 4; ++ni) {
      const int col = bn + wc * 64 + ni * 16 + lm;
      float bb = 0.f;
      if (HAS_BIAS) bb = bias[col];
#pragma unroll
      for (int r = 0; r < 4; ++r) {
        const int row = bm + wr * 64 + mi * 16 + lg * 4 + r;
        const float v = acc[mi][ni][r] + bb;
        if (OUT_F32) reinterpret_cast<float*>(Cv)[(size_t)row * N + col] = v;
        else reinterpret_cast<uint16_t*>(Cv)[(size_t)row * N + col] = f2bf(v);
      }
    }
  }
}

// ---------------- RoPE + scatter, vectorized (Q scaled by 1/sqrt(D)*log2e) ----------------
#define SC_Q 0.1275523865396698f  // 0.08838834764831845 * 1.44269504088896341

__global__ __launch_bounds__(320) void rope_scatter(const uint16_t* __restrict__ raw,
                                                    const float* __restrict__ cosp,
                                                    const float* __restrict__ sinp,
                                                    uint16_t* __restrict__ Qo,
                                                    uint16_t* __restrict__ Ko) {
  const int c8 = threadIdx.x;            // 0..319 (chunk of 8 elems)
  const int m = blockIdx.x;              // 0..4095
  const int b = m >> 11, tt = m & 2047;
  const int c = c8 * 8;                  // 0..2552
  const int d = c & 127;
  const size_t rowoff = (size_t)m * 3072;
  union { short8 v; uint16_t s[8]; } x8, p8, o8;
  x8.v = *reinterpret_cast<const short8*>(raw + rowoff + c);
  p8.v = *reinterpret_cast<const short8*>(raw + rowoff + (c ^ 64));
  const float* cb = cosp + ((size_t)b * T_ + tt) * D_ + d;
  const float* sb = sinp + ((size_t)b * T_ + tt) * D_ + d;
  const bool isq = (c < 2048);
  const float scale = isq ? SC_Q : 1.0f;
  const float sgn = (d < 64) ? -1.f : 1.f;
#pragma unroll
  for (int j = 0; j < 8; ++j) {
    const float x = bf2f(x8.s[j]);
    const float px = bf2f(p8.s[j]);
    o8.s[j] = f2bf((x * cb[j] + sgn * px * sb[j]) * scale);
  }
  if (isq) {
    const int hh = c >> 7;
    *reinterpret_cast<short8*>(Qo + (((size_t)(b * H_ + hh)) * T_ + tt) * D_ + d) = o8.v;
  } else {
    const int hh = (c - 2048) >> 7;
    *reinterpret_cast<short8*>(Ko + (((size_t)(b * KVH_ + hh)) * T_ + tt) * D_ + d) = o8.v;
  }
}

// ---------------- V transpose: qkvraw cols 2560..3071 -> VtG[b][kvh][d][t] ----------------
__global__ __launch_bounds__(256) void transpose_v(const uint16_t* __restrict__ raw,
                                                   uint16_t* __restrict__ VtG) {
  const int hb = blockIdx.y;            // b*4+kvh, 0..7
  const int b = hb >> 2, kvh = hb & 3;
  const int d = threadIdx.x & 127;
  const int tw = threadIdx.x >> 7;      // 0..1
  const int t0 = blockIdx.x * 16 + tw * 8;
  const uint16_t* src = raw + ((size_t)(b * T_ + t0)) * 3072 + 2560 + kvh * 128 + d;
  union { uint16_t s[8]; short8 v; } pk;
#pragma unroll
  for (int j = 0; j < 8; ++j) pk.s[j] = src[(size_t)j * 3072];
  *reinterpret_cast<short8*>(VtG + ((size_t)hb * D_ + d) * T_ + t0) = pk.v;
}

// ---------------- causal GQA flash attention ----------------
// QBLK=128 (32 q-rows/wave, 2 m-frags), KVBLK=64.
// K LDS: linear [64][128] with chunk-XOR swizzle (c16 ^= row&7) applied on the
//        GLOBAL source at stage time and on the LDS read offset (m173 pattern).
// Vt LDS: linear [128][64], chunk-XOR (c8 ^= row&7), same scheme.
// P LDS: padded [32][72] per wave (odd 16B granule -> conflict-free b128 reads).
#define KVBLK 64
#define PPAD 72

__global__ __launch_bounds__(256, 3) void attn_fwd(const uint16_t* __restrict__ Qb,
                                                   const uint16_t* __restrict__ Kb,
                                                   const uint16_t* __restrict__ VtG,
                                                   uint16_t* __restrict__ Ab) {
  __shared__ __align__(16) uint16_t Kl[KVBLK * D_];      // 16384 B
  __shared__ __align__(16) uint16_t Vtl[D_ * KVBLK];     // 16384 B
  __shared__ __align__(16) uint16_t Pl[4 * 32 * PPAD];   // 18432 B  (total 51200 -> 3 blk/CU)
  const int tid = threadIdx.x;
  const int w = tid >> 6, lane = tid & 63;
  const int lm = lane & 15, lg = lane >> 4;
  const int bh = blockIdx.y;
  const int b = bh >> 4, h = bh & 15;
  const int kvh = h >> 2;
  const int qt = (blockIdx.x + bh) & 15;   // load-balance swizzle, 16 q-tiles of 128
  const int q0 = qt * 128;
  const int wrow0 = q0 + w * 32;           // this wave's first q-row

  // Q fragments: 2 m-frags x 4 k-frags (Q pre-scaled by SC_Q at rope time)
  const uint16_t* Qw = Qb + (((size_t)(b * H_ + h)) * T_ + wrow0) * D_;
  short8 qf[2][4];
#pragma unroll
  for (int mi = 0; mi < 2; ++mi)
#pragma unroll
    for (int kk = 0; kk < 4; ++kk)
      qf[mi][kk] = *reinterpret_cast<const short8*>(Qw + (size_t)(mi * 16 + lm) * D_ + kk * 32 + lg * 8);

  f32x4 o[2][8];
  const f32x4 z4 = {0.f, 0.f, 0.f, 0.f};
#pragma unroll
  for (int mi = 0; mi < 2; ++mi)
#pragma unroll
    for (int f = 0; f < 8; ++f) o[mi][f] = z4;
  float mrow[2][4], lrow[2][4];
#pragma unroll
  for (int mi = 0; mi < 2; ++mi)
#pragma unroll
    for (int r = 0; r < 4; ++r) { mrow[mi][r] = -1e30f; lrow[mi][r] = 0.f; }

  const uint16_t* Kbase = Kb + ((size_t)(b * KVH_ + kvh)) * T_ * D_;
  const uint16_t* Vtbase = VtG + ((size_t)(b * KVH_ + kvh)) * D_ * T_;
  uint16_t* Pw = Pl + w * 32 * PPAD;

  const int nkv = 2 * qt + 2;
  for (int t = 0; t < nkv; ++t) {
    const int kv0 = t * KVBLK;
    __syncthreads();  // prior tile's LDS reads done before restage
    // stage K [64 rows][16 chunks] and Vt [128 rows][8 chunks] via global_load_lds,
    // LDS linear, global source chunk-XOR-swizzled.
#pragma unroll
    for (int it = 0; it < 4; ++it) {
      const int chunk = it * 256 + tid;          // this lane's chunk
      {
        const int r = chunk >> 4, c16 = chunk & 15;
        const uint16_t* g = Kbase + (size_t)(kv0 + r) * D_ + ((c16 ^ (r & 7)) * 8);
        __builtin_amdgcn_global_load_lds((const __attribute__((address_space(1))) unsigned int*)g,
                                         (__attribute__((address_space(3))) unsigned int*)(Kl + (it * 256 + w * 64) * 8),
                                         16, 0, 0);
      }
      {
        const int dd = chunk >> 3, c8 = chunk & 7;
        const uint16_t* g = Vtbase + (size_t)dd * T_ + kv0 + ((c8 ^ (dd & 7)) * 8);
        __builtin_amdgcn_global_load_lds((const __attribute__((address_space(1))) unsigned int*)g,
                                         (__attribute__((address_space(3))) unsigned int*)(Vtl + (it * 256 + w * 64) * 8),
                                         16, 0, 0);
      }
    }
    __syncthreads();

    // S = Q K^T : 2 m-frags x 4 col-frags x 4 k-frags
    f32x4 s[2][4];
#pragma unroll
    for (int mi = 0; mi < 2; ++mi)
#pragma unroll
      for (int nf = 0; nf < 4; ++nf) s[mi][nf] = z4;
#pragma unroll
    for (int nf = 0; nf < 4; ++nf)
#pragma unroll
      for (int kk = 0; kk < 4; ++kk) {
        const int row = nf * 16 + lm;
        const short8 kf = *reinterpret_cast<const short8*>(Kl + row * D_ + (((kk * 4 + lg) ^ (row & 7)) * 8));
#pragma unroll
        for (int mi = 0; mi < 2; ++mi)
          s[mi][nf] = __builtin_amdgcn_mfma_f32_16x16x32_bf16(qf[mi][kk], kf, s[mi][nf], 0, 0, 0);
      }

    // causal mask (only tiles this wave's rows intersect)
    if (kv0 + KVBLK - 1 > wrow0) {
#pragma unroll
      for (int mi = 0; mi < 2; ++mi)
#pragma unroll
        for (int nf = 0; nf < 4; ++nf) {
          const int colg = kv0 + nf * 16 + lm;
#pragma unroll
          for (int r = 0; r < 4; ++r) {
            const int rowg = wrow0 + mi * 16 + lg * 4 + r;
            if (colg > rowg) s[mi][nf][r] = -1e30f;
          }
        }
    }

    float tmax[2][4];
#pragma unroll
    for (int mi = 0; mi < 2; ++mi)
#pragma unroll
      for (int r = 0; r < 4; ++r) {
        float v = fmaxf(fmaxf(s[mi][0][r], s[mi][1][r]), fmaxf(s[mi][2][r], s[mi][3][r]));
        v = fmaxf(v, __shfl_xor(v, 1));
        v = fmaxf(v, __shfl_xor(v, 2));
        v = fmaxf(v, __shfl_xor(v, 4));
        v = fmaxf(v, __shfl_xor(v, 8));
        tmax[mi][r] = v;
      }
    // defer-max: skip rescale unless tile max grew past threshold
    bool grow = false;
#pragma unroll
    for (int mi = 0; mi < 2; ++mi)
#pragma unroll
      for (int r = 0; r < 4; ++r) grow = grow || (tmax[mi][r] > mrow[mi][r] + 8.f);
    if (__any((int)grow)) {
#pragma unroll
      for (int mi = 0; mi < 2; ++mi)
#pragma unroll
        for (int r = 0; r < 4; ++r) {
          const float nm = fmaxf(mrow[mi][r], tmax[mi][r]);
          const float al = exp2f(mrow[mi][r] - nm);
          mrow[mi][r] = nm;
          lrow[mi][r] *= al;
#pragma unroll
          for (int f = 0; f < 8; ++f) o[mi][f][r] *= al;
        }
    }
    float rsum[2][4] = {{0.f, 0.f, 0.f, 0.f}, {0.f, 0.f, 0.f, 0.f}};
#pragma unroll
    for (int mi = 0; mi < 2; ++mi)
#pragma unroll
      for (int nf = 0; nf < 4; ++nf)
#pragma unroll
        for (int r = 0; r < 4; ++r) {
          const float p = exp2f(s[mi][nf][r] - mrow[mi][r]);
          rsum[mi][r] += p;
          Pw[(mi * 16 + lg * 4 + r) * PPAD + nf * 16 + lm] = hwbf(p);
        }
#pragma unroll
    for (int mi = 0; mi < 2; ++mi)
#pragma unroll
      for (int r = 0; r < 4; ++r) {
        float v = rsum[mi][r];
        v += __shfl_xor(v, 1);
        v += __shfl_xor(v, 2);
        v += __shfl_xor(v, 4);
        v += __shfl_xor(v, 8);
        lrow[mi][r] += v;
      }
    // P is wave-private: drain ds_writes; no cross-wave barrier needed
    asm volatile("s_waitcnt lgkmcnt(0)" ::: "memory");
    short8 pf[2][2];
#pragma unroll
    for (int mi = 0; mi < 2; ++mi)
#pragma unroll
      for (int ks = 0; ks < 2; ++ks)
        pf[mi][ks] = *reinterpret_cast<const short8*>(Pw + (mi * 16 + lm) * PPAD + ks * 32 + lg * 8);
#pragma unroll
    for (int f = 0; f < 8; ++f)
#pragma unroll
      for (int ks = 0; ks < 2; ++ks) {
        const int dd = f * 16 + lm;
        const short8 vf = *reinterpret_cast<const short8*>(Vtl + dd * KVBLK + (((ks * 4 + lg) ^ (dd & 7)) * 8));
#pragma unroll
        for (int mi = 0; mi < 2; ++mi)
          o[mi][f] = __builtin_amdgcn_mfma_f32_16x16x32_bf16(pf[mi][ks], vf, o[mi][f], 0, 0, 0);
      }
  }

#pragma unroll
  for (int mi = 0; mi < 2; ++mi) {
    float rcp[4];
#pragma unroll
    for (int r = 0; r < 4; ++r) rcp[r] = 1.0f / lrow[mi][r];
#pragma unroll
    for (int f = 0; f < 8; ++f) {
      const int col = h * D_ + f * 16 + lm;
#pragma unroll
      for (int r = 0; r < 4; ++r) {
        const int trow = wrow0 + mi * 16 + lg * 4 + r;
        Ab[((size_t)(b * T_ + trow)) * (H_ * D_) + col] = f2bf(o[mi][f][r] * rcp[r]);
      }
    }
  }
}

// ---------------- launch ----------------
extern "C" void kernel_launch(void* const* d_in, const int* in_sizes, int n_in,
                              void* d_out, int out_size, void* d_ws, size_t ws_size,
                              hipStream_t stream) {
  const float* hidden = (const float*)d_in[0];
  const float* cosp   = (const float*)d_in[1];
  const float* sinp   = (const float*)d_in[2];
  // d_in[3] = attention_mask: exactly causal, implemented in-kernel
  const float* Wq = (const float*)d_in[4];
  const float* bq = (const float*)d_in[5];
  const float* Wk = (const float*)d_in[6];
  const float* bk = (const float*)d_in[7];
  const float* Wv = (const float*)d_in[8];
  const float* bv = (const float*)d_in[9];
  const float* Wo = (const float*)d_in[10];

  char* ws = (char*)d_ws;
  uint16_t* hidb   = (uint16_t*)(ws);              // 4096x2048 bf16   16,777,216 B
  uint16_t* wqkv   = (uint16_t*)(ws + 16777216);   // 3072x2048 bf16   12,582,912 B
  uint16_t* wob    = (uint16_t*)(ws + 29360128);   // 2048x2048 bf16    8,388,608 B
  float*    biasq  = (float*)   (ws + 37748736);   // 3072 f32             12,288 B
  uint16_t* qkvraw = (uint16_t*)(ws + 37761024);   // 4096x3072 bf16   25,165,824 B
  uint16_t* Qb     = (uint16_t*)(ws + 62926848);   // [2][16][2048][128] 16,777,216 B
  uint16_t* Kb     = (uint16_t*)(ws + 79704064);   // [2][4][2048][128]   4,194,304 B
  uint16_t* VtG    = (uint16_t*)(ws + 83898368);   // [2][4][128][2048]   4,194,304 B
  uint16_t* Ab     = (uint16_t*)(ws + 88092672);   // [2][2048][2048]   16,777,216 B

  cvt_f32_bf16<<<8192, 256, 0, stream>>>(hidden, hidb, 8388608);
  cvt_f32_bf16<<<4096, 256, 0, stream>>>(Wq, wqkv, 4194304);
  cvt_f32_bf16<<<1024, 256, 0, stream>>>(Wk, wqkv + 4194304, 1048576);
  cvt_f32_bf16<<<1024, 256, 0, stream>>>(Wv, wqkv + 5242880, 1048576);
  cvt_f32_bf16<<<4096, 256, 0, stream>>>(Wo, wob, 4194304);
  concat_bias<<<12, 256, 0, stream>>>(bq, bk, bv, biasq);

  // QKV projection: [4096,2048] x [3072,2048]^T -> [4096,3072] (+bias)
  gemm_bt<false, true><<<dim3(24, 32), 256, 0, stream>>>(hidb, wqkv, qkvraw, biasq, 4096, 3072, 2048);
  // RoPE + scatter Q,K (Q pre-scaled by 1/sqrt(D)*log2e)
  rope_scatter<<<4096, 320, 0, stream>>>(qkvraw, cosp, sinp, Qb, Kb);
  // V transpose to [d][t]
  transpose_v<<<dim3(128, 8), 256, 0, stream>>>(qkvraw, VtG);
  // causal GQA flash attention -> Ab [b][t][h*128+d] bf16
  attn_fwd<<<dim3(16, 32), 256, 0, stream>>>(Qb, Kb, VtG, Ab);
  // output projection: [4096,2048] x [2048,2048]^T -> d_out fp32
  gemm_bt<true, false><<<dim3(16, 32), 256, 0, stream>>>(Ab, wob, d_out, nullptr, 4096, 2048, 2048);
}